// Round 12
// baseline (410.924 us; speedup 1.0000x reference)
//
#include <hip/hip_runtime.h>
#include <hip/hip_bf16.h>
#include <hip/hip_cooperative_groups.h>

namespace cg = cooperative_groups;

#define NB_B 16
#define NH 16
#define NBLK 32
#define BSZ 128
#define DH 64
#define DM 1024
#define KVLEN 4096
#define NCH 8
#define CHUNK 512

// ===================== fused cooperative version =====================
// QKV -> grid.sync -> attn partials -> grid.sync -> reduce -> grid.sync
// -> out projection. __launch_bounds__(256,4) caps VGPR at 128 so 4
// blocks/CU are guaranteed -> 1024 blocks co-resident on 256 CUs.
__global__ __launch_bounds__(256, 4) void fused_all(
    const float* __restrict__ hs,
    const float* __restrict__ kc, const float* __restrict__ vc,
    const float* __restrict__ mask,
    const int* __restrict__ cpos, const int* __restrict__ bt,
    const float* __restrict__ Wq, const float* __restrict__ bq,
    const float* __restrict__ Wk, const float* __restrict__ bk,
    const float* __restrict__ Wv, const float* __restrict__ bv,
    const float* __restrict__ Wo, const float* __restrict__ bo,
    float* __restrict__ ws_qkv,
    float* __restrict__ pm, float* __restrict__ pl, float* __restrict__ pctx,
    float* __restrict__ ctxf, float* __restrict__ out)
{
    cg::grid_group grid = cg::this_grid();
    int bid = blockIdx.x;
    int tid = threadIdx.x;

    __shared__ float gm[32], glv[32];
    __shared__ float gctx[32][DH];

    // ---------- Phase 1: QKV projections (blocks 0..383) ----------
    if (bid < 384) {
        int grp = tid >> 5, gl = tid & 31;
        int row = bid * 8 + grp;            // 0 .. 3*DM-1
        int mm = row >> 10;                 // 0=q,1=k,2=v
        int o = row & (DM - 1);
        const float* W    = (mm == 0) ? Wq : (mm == 1) ? Wk : Wv;
        const float* bias = (mm == 0) ? bq : (mm == 1) ? bk : bv;
        const float4* wrow = (const float4*)(W + (size_t)o * DM);
        float4 w[8];
#pragma unroll
        for (int k = 0; k < 8; ++k) w[k] = wrow[gl + 32 * k];
        float bb = bias[o];

        for (int b = 0; b < NB_B; ++b) {
            const float4* x = (const float4*)(hs + (size_t)b * DM);
            float acc = 0.f;
#pragma unroll
            for (int k = 0; k < 8; ++k) {
                float4 xv = x[gl + 32 * k];
                acc += w[k].x * xv.x + w[k].y * xv.y + w[k].z * xv.z + w[k].w * xv.w;
            }
            acc += __shfl_xor(acc, 1);
            acc += __shfl_xor(acc, 2);
            acc += __shfl_xor(acc, 4);
            acc += __shfl_xor(acc, 8);
            acc += __shfl_xor(acc, 16);
            if (gl == 0)
                ws_qkv[(size_t)mm * (NB_B * DM) + (size_t)b * DM + o] = acc + bb;
        }
    }
    grid.sync();

    // ---------- Phase 2: attention partials (all blocks, 2 chunks) ----
    // bh = bid & 255 -> bid == bh (mod 8): all chunks of a (b,h) on one
    // XCD (L2 reuse of duplicate physical blocks), balanced across XCDs.
    {
        int bh = bid & 255;
        int b  = bh >> 4;
        int h  = bh & (NH - 1);
        int wave = tid >> 6, lane = tid & 63;
        int g = lane >> 3, gl = lane & 7;   // 8 groups of 8 lanes per wave
        int gid = wave * 8 + g;

        int pos = cpos[b];
        int nvalid = pos + 1;

        const float* q    = ws_qkv + (size_t)b * DM + h * DH;
        const float* knew = ws_qkv + (size_t)NB_B * DM + (size_t)b * DM + h * DH;
        const float* vnew = ws_qkv + (size_t)2 * NB_B * DM + (size_t)b * DM + h * DH;

        float4 qv0 = ((const float4*)q)[gl * 2];
        float4 qv1 = ((const float4*)q)[gl * 2 + 1];
        int phys_new = bt[b * NBLK + (pos >> 7)];
        int off_new  = pos & (BSZ - 1);

        const float* mrow = mask + (size_t)bh * KVLEN;
        const int* btrow = bt + b * NBLK;
        const unsigned bh_base = (unsigned)bh * NBLK;

        for (int cc = 0; cc < 2; ++cc) {
            int c = (bid >> 8) + cc * 4;    // {0..3} then {4..7}
            int start = c * CHUNK;
            int end = min(start + CHUNK, nvalid);

            float m = -1e30f, l = 0.f;
            float4 ctx0 = {0.f, 0.f, 0.f, 0.f};
            float4 ctx1 = {0.f, 0.f, 0.f, 0.f};

            int n = end - start;
            if (n > 0) {
                int nfull = n >> 5;
                int jg = start + wave * 8 + g;
#pragma unroll 2
                for (int it = 0; it < nfull; ++it) {
                    int j = jg + it * 32;
                    int blk = j >> 7;
                    int p = j & (BSZ - 1);
                    int ph = btrow[blk];
                    bool isnew = (ph == phys_new) && (p == off_new);
                    unsigned coff = ((bh_base + (unsigned)ph) * BSZ + (unsigned)p) * DH;
                    const float4* kp = (const float4*)(isnew ? knew : (kc + coff));
                    const float4* vp = (const float4*)(isnew ? vnew : (vc + coff));
                    float4 k0 = kp[gl * 2], k1 = kp[gl * 2 + 1];
                    float4 v0 = vp[gl * 2], v1 = vp[gl * 2 + 1];
                    float sd = qv0.x * k0.x + qv0.y * k0.y + qv0.z * k0.z + qv0.w * k0.w
                             + qv1.x * k1.x + qv1.y * k1.y + qv1.z * k1.z + qv1.w * k1.w;
                    sd += __shfl_xor(sd, 1);
                    sd += __shfl_xor(sd, 2);
                    sd += __shfl_xor(sd, 4);
                    float sc = sd + mrow[j];
                    float newm = fmaxf(m, sc);
                    float scale = __expf(m - newm);
                    float pr = __expf(sc - newm);
                    l = l * scale + pr;
                    ctx0.x = ctx0.x * scale + pr * v0.x;
                    ctx0.y = ctx0.y * scale + pr * v0.y;
                    ctx0.z = ctx0.z * scale + pr * v0.z;
                    ctx0.w = ctx0.w * scale + pr * v0.w;
                    ctx1.x = ctx1.x * scale + pr * v1.x;
                    ctx1.y = ctx1.y * scale + pr * v1.y;
                    ctx1.z = ctx1.z * scale + pr * v1.z;
                    ctx1.w = ctx1.w * scale + pr * v1.w;
                    m = newm;
                }
                if (n & 31) {
                    int j = jg + nfull * 32;
                    bool valid = (j < end);
                    float4 k0 = {0,0,0,0}, k1 = {0,0,0,0};
                    float4 v0 = {0,0,0,0}, v1 = {0,0,0,0};
                    float msk = 0.f;
                    if (valid) {
                        int blk = j >> 7;
                        int p = j & (BSZ - 1);
                        int ph = btrow[blk];
                        bool isnew = (ph == phys_new) && (p == off_new);
                        unsigned coff = ((bh_base + (unsigned)ph) * BSZ + (unsigned)p) * DH;
                        const float4* kp = (const float4*)(isnew ? knew : (kc + coff));
                        const float4* vp = (const float4*)(isnew ? vnew : (vc + coff));
                        k0 = kp[gl * 2]; k1 = kp[gl * 2 + 1];
                        v0 = vp[gl * 2]; v1 = vp[gl * 2 + 1];
                        msk = mrow[j];
                    }
                    float sd = qv0.x * k0.x + qv0.y * k0.y + qv0.z * k0.z + qv0.w * k0.w
                             + qv1.x * k1.x + qv1.y * k1.y + qv1.z * k1.z + qv1.w * k1.w;
                    sd += __shfl_xor(sd, 1);
                    sd += __shfl_xor(sd, 2);
                    sd += __shfl_xor(sd, 4);
                    float sc = valid ? (sd + msk) : -1e30f;
                    float newm = fmaxf(m, sc);
                    float scale = __expf(m - newm);
                    float pr = valid ? __expf(sc - newm) : 0.f;
                    l = l * scale + pr;
                    ctx0.x = ctx0.x * scale + pr * v0.x;
                    ctx0.y = ctx0.y * scale + pr * v0.y;
                    ctx0.z = ctx0.z * scale + pr * v0.z;
                    ctx0.w = ctx0.w * scale + pr * v0.w;
                    ctx1.x = ctx1.x * scale + pr * v1.x;
                    ctx1.y = ctx1.y * scale + pr * v1.y;
                    ctx1.z = ctx1.z * scale + pr * v1.z;
                    ctx1.w = ctx1.w * scale + pr * v1.w;
                    m = newm;
                }
            }

            if (gl == 0) { gm[gid] = m; glv[gid] = l; }
            *((float4*)&gctx[gid][gl * 8])     = ctx0;
            *((float4*)&gctx[gid][gl * 8 + 4]) = ctx1;
            __syncthreads();

            if (tid < DH) {
                int d = tid;
                float M = -1e30f;
#pragma unroll
                for (int i = 0; i < 32; ++i) M = fmaxf(M, gm[i]);
                float L = 0.f, acc = 0.f;
#pragma unroll
                for (int i = 0; i < 32; ++i) {
                    float w = __expf(gm[i] - M);
                    L += w * glv[i];
                    acc += w * gctx[i][d];
                }
                size_t pi = (size_t)bh * NCH + c;
                if (d == 0) { pm[pi] = M; pl[pi] = L; }
                pctx[pi * DH + d] = acc;
            }
            __syncthreads();
        }
    }
    grid.sync();

    // ---------- Phase 3: cross-chunk reduce (blocks 0..255) ------
    if (bid < 256 && tid < DH) {
        int bh = bid;
        int d = tid;
        int b = bh >> 4, h = bh & (NH - 1);
        int pos = cpos[b];
        int nch_b = (pos + CHUNK) >> 9;     // ceil((pos+1)/512)
        float M = -1e30f;
        for (int ci = 0; ci < nch_b; ++ci)
            M = fmaxf(M, pm[(size_t)bh * NCH + ci]);
        float L = 0.f, acc = 0.f;
        for (int ci = 0; ci < nch_b; ++ci) {
            float w = __expf(pm[(size_t)bh * NCH + ci] - M);
            L += w * pl[(size_t)bh * NCH + ci];
            acc += w * pctx[((size_t)bh * NCH + ci) * DH + d];
        }
        ctxf[(size_t)b * DM + h * DH + d] = acc / L;
    }
    grid.sync();

    // ---------- Phase 4: output projection (blocks 0..127) ----------
    if (bid < 128) {
        int grp = tid >> 5, gl = tid & 31;
        int o = bid * 8 + grp;              // 0 .. DM-1
        const float4* wrow = (const float4*)(Wo + (size_t)o * DM);
        float4 w[8];
#pragma unroll
        for (int k = 0; k < 8; ++k) w[k] = wrow[gl + 32 * k];
        float bb = bo[o];

        for (int b = 0; b < NB_B; ++b) {
            const float4* x = (const float4*)(ctxf + (size_t)b * DM);
            float acc = 0.f;
#pragma unroll
            for (int k = 0; k < 8; ++k) {
                float4 xv = x[gl + 32 * k];
                acc += w[k].x * xv.x + w[k].y * xv.y + w[k].z * xv.z + w[k].w * xv.w;
            }
            acc += __shfl_xor(acc, 1);
            acc += __shfl_xor(acc, 2);
            acc += __shfl_xor(acc, 4);
            acc += __shfl_xor(acc, 8);
            acc += __shfl_xor(acc, 16);
            if (gl == 0)
                out[(size_t)b * DM + o] = acc + bb;
        }
    }
}

// ===================== fallback: proven R10 4-kernel path =====================
__global__ __launch_bounds__(256) void qkv_all(
    const float* __restrict__ hs,
    const float* __restrict__ Wq, const float* __restrict__ bq,
    const float* __restrict__ Wk, const float* __restrict__ bk,
    const float* __restrict__ Wv, const float* __restrict__ bv,
    float* __restrict__ ws)
{
    __shared__ float sh[NB_B][DM];
    int tid = threadIdx.x;
#pragma unroll
    for (int i = 0; i < 16; ++i) {
        int idx = i * 256 + tid;
        ((float4*)sh)[idx] = ((const float4*)hs)[idx];
    }
    __syncthreads();

    int grp = tid >> 5, gl = tid & 31;
    int row = blockIdx.x * 8 + grp;
    int m = row >> 10;
    int o = row & (DM - 1);
    const float* W    = (m == 0) ? Wq : (m == 1) ? Wk : Wv;
    const float* bias = (m == 0) ? bq : (m == 1) ? bk : bv;
    const float4* wrow = (const float4*)(W + (size_t)o * DM);
    float4 w[8];
#pragma unroll
    for (int k = 0; k < 8; ++k) w[k] = wrow[gl + 32 * k];
    float bb = bias[o];

    for (int b = 0; b < NB_B; ++b) {
        const float4* x = (const float4*)sh[b];
        float acc = 0.f;
#pragma unroll
        for (int k = 0; k < 8; ++k) {
            float4 xv = x[gl + 32 * k];
            acc += w[k].x * xv.x + w[k].y * xv.y + w[k].z * xv.z + w[k].w * xv.w;
        }
        acc += __shfl_xor(acc, 1);
        acc += __shfl_xor(acc, 2);
        acc += __shfl_xor(acc, 4);
        acc += __shfl_xor(acc, 8);
        acc += __shfl_xor(acc, 16);
        if (gl == 0)
            ws[(size_t)m * (NB_B * DM) + (size_t)b * DM + o] = acc + bb;
    }
}

__global__ __launch_bounds__(128) void out_all(
    const float* __restrict__ ctx, const float* __restrict__ Wo,
    const float* __restrict__ bo, float* __restrict__ out)
{
    __shared__ float sh[NB_B][DM];
    int tid = threadIdx.x;
#pragma unroll
    for (int i = 0; i < 32; ++i) {
        int idx = i * 128 + tid;
        ((float4*)sh)[idx] = ((const float4*)ctx)[idx];
    }
    __syncthreads();

    int grp = tid >> 5, gl = tid & 31;
    int o = blockIdx.x * 4 + grp;
    const float4* wrow = (const float4*)(Wo + (size_t)o * DM);
    float4 w[8];
#pragma unroll
    for (int k = 0; k < 8; ++k) w[k] = wrow[gl + 32 * k];
    float bb = bo[o];

    for (int b = 0; b < NB_B; ++b) {
        const float4* x = (const float4*)sh[b];
        float acc = 0.f;
#pragma unroll
        for (int k = 0; k < 8; ++k) {
            float4 xv = x[gl + 32 * k];
            acc += w[k].x * xv.x + w[k].y * xv.y + w[k].z * xv.z + w[k].w * xv.w;
        }
        acc += __shfl_xor(acc, 1);
        acc += __shfl_xor(acc, 2);
        acc += __shfl_xor(acc, 4);
        acc += __shfl_xor(acc, 8);
        acc += __shfl_xor(acc, 16);
        if (gl == 0)
            out[(size_t)b * DM + o] = acc + bb;
    }
}

__global__ __launch_bounds__(256) void attn_partial(
    const float* __restrict__ kc, const float* __restrict__ vc,
    const float* __restrict__ mask,
    const int* __restrict__ cpos, const int* __restrict__ bt,
    const float* __restrict__ wsin,
    float* __restrict__ pm, float* __restrict__ pl, float* __restrict__ pctx)
{
    int id = blockIdx.x;
    int c  = id >> 8;
    int bh = id & 255;
    int b  = bh >> 4;
    int h  = bh & (NH - 1);

    int tid = threadIdx.x;
    int wave = tid >> 6, lane = tid & 63;
    int g = lane >> 3, gl = lane & 7;

    int pos = cpos[b];
    int nvalid = pos + 1;
    int start = c * CHUNK;
    int end = min(start + CHUNK, nvalid);

    const float* q    = wsin + (size_t)b * DM + h * DH;
    const float* knew = wsin + (size_t)NB_B * DM + (size_t)b * DM + h * DH;
    const float* vnew = wsin + (size_t)2 * NB_B * DM + (size_t)b * DM + h * DH;

    float4 qv0 = ((const float4*)q)[gl * 2];
    float4 qv1 = ((const float4*)q)[gl * 2 + 1];
    int phys_new = bt[b * NBLK + (pos >> 7)];
    int off_new  = pos & (BSZ - 1);

    const float* mrow = mask + (size_t)bh * KVLEN;
    const int* btrow = bt + b * NBLK;
    const unsigned bh_base = (unsigned)bh * NBLK;

    float m = -1e30f, l = 0.f;
    float4 ctx0 = {0.f, 0.f, 0.f, 0.f};
    float4 ctx1 = {0.f, 0.f, 0.f, 0.f};

    int n = end - start;
    if (n > 0) {
        int nfull = n >> 5;
        int jg = start + wave * 8 + g;
#pragma unroll 2
        for (int it = 0; it < nfull; ++it) {
            int j = jg + it * 32;
            int blk = j >> 7;
            int p = j & (BSZ - 1);
            int ph = btrow[blk];
            bool isnew = (ph == phys_new) && (p == off_new);
            unsigned coff = ((bh_base + (unsigned)ph) * BSZ + (unsigned)p) * DH;
            const float4* kp = (const float4*)(isnew ? knew : (kc + coff));
            const float4* vp = (const float4*)(isnew ? vnew : (vc + coff));
            float4 k0 = kp[gl * 2], k1 = kp[gl * 2 + 1];
            float4 v0 = vp[gl * 2], v1 = vp[gl * 2 + 1];
            float sd = qv0.x * k0.x + qv0.y * k0.y + qv0.z * k0.z + qv0.w * k0.w
                     + qv1.x * k1.x + qv1.y * k1.y + qv1.z * k1.z + qv1.w * k1.w;
            sd += __shfl_xor(sd, 1);
            sd += __shfl_xor(sd, 2);
            sd += __shfl_xor(sd, 4);
            float sc = sd + mrow[j];
            float newm = fmaxf(m, sc);
            float scale = __expf(m - newm);
            float pr = __expf(sc - newm);
            l = l * scale + pr;
            ctx0.x = ctx0.x * scale + pr * v0.x;
            ctx0.y = ctx0.y * scale + pr * v0.y;
            ctx0.z = ctx0.z * scale + pr * v0.z;
            ctx0.w = ctx0.w * scale + pr * v0.w;
            ctx1.x = ctx1.x * scale + pr * v1.x;
            ctx1.y = ctx1.y * scale + pr * v1.y;
            ctx1.z = ctx1.z * scale + pr * v1.z;
            ctx1.w = ctx1.w * scale + pr * v1.w;
            m = newm;
        }
        if (n & 31) {
            int j = jg + nfull * 32;
            bool valid = (j < end);
            float4 k0 = {0,0,0,0}, k1 = {0,0,0,0};
            float4 v0 = {0,0,0,0}, v1 = {0,0,0,0};
            float msk = 0.f;
            if (valid) {
                int blk = j >> 7;
                int p = j & (BSZ - 1);
                int ph = btrow[blk];
                bool isnew = (ph == phys_new) && (p == off_new);
                unsigned coff = ((bh_base + (unsigned)ph) * BSZ + (unsigned)p) * DH;
                const float4* kp = (const float4*)(isnew ? knew : (kc + coff));
                const float4* vp = (const float4*)(isnew ? vnew : (vc + coff));
                k0 = kp[gl * 2]; k1 = kp[gl * 2 + 1];
                v0 = vp[gl * 2]; v1 = vp[gl * 2 + 1];
                msk = mrow[j];
            }
            float sd = qv0.x * k0.x + qv0.y * k0.y + qv0.z * k0.z + qv0.w * k0.w
                     + qv1.x * k1.x + qv1.y * k1.y + qv1.z * k1.z + qv1.w * k1.w;
            sd += __shfl_xor(sd, 1);
            sd += __shfl_xor(sd, 2);
            sd += __shfl_xor(sd, 4);
            float sc = valid ? (sd + msk) : -1e30f;
            float newm = fmaxf(m, sc);
            float scale = __expf(m - newm);
            float pr = valid ? __expf(sc - newm) : 0.f;
            l = l * scale + pr;
            ctx0.x = ctx0.x * scale + pr * v0.x;
            ctx0.y = ctx0.y * scale + pr * v0.y;
            ctx0.z = ctx0.z * scale + pr * v0.z;
            ctx0.w = ctx0.w * scale + pr * v0.w;
            ctx1.x = ctx1.x * scale + pr * v1.x;
            ctx1.y = ctx1.y * scale + pr * v1.y;
            ctx1.z = ctx1.z * scale + pr * v1.z;
            ctx1.w = ctx1.w * scale + pr * v1.w;
            m = newm;
        }
    }

    __shared__ float gm[32], glv[32];
    __shared__ float gctx[32][DH];
    int gid = wave * 8 + g;
    if (gl == 0) { gm[gid] = m; glv[gid] = l; }
    *((float4*)&gctx[gid][gl * 8])     = ctx0;
    *((float4*)&gctx[gid][gl * 8 + 4]) = ctx1;
    __syncthreads();

    if (tid < DH) {
        int d = tid;
        float M = -1e30f;
#pragma unroll
        for (int i = 0; i < 32; ++i) M = fmaxf(M, gm[i]);
        float L = 0.f, acc = 0.f;
#pragma unroll
        for (int i = 0; i < 32; ++i) {
            float w = __expf(gm[i] - M);
            L += w * glv[i];
            acc += w * gctx[i][d];
        }
        size_t pi = (size_t)bh * NCH + c;
        if (d == 0) { pm[pi] = M; pl[pi] = L; }
        pctx[pi * DH + d] = acc;
    }
}

__global__ __launch_bounds__(64) void attn_reduce(
    const float* __restrict__ pm, const float* __restrict__ pl,
    const float* __restrict__ pctx, float* __restrict__ ctx_out)
{
    int bh = blockIdx.x;
    int d = threadIdx.x;
    float M = -1e30f;
#pragma unroll
    for (int ci = 0; ci < NCH; ++ci) M = fmaxf(M, pm[(size_t)bh * NCH + ci]);
    float L = 0.f, acc = 0.f;
#pragma unroll
    for (int ci = 0; ci < NCH; ++ci) {
        float w = __expf(pm[(size_t)bh * NCH + ci] - M);
        L += w * pl[(size_t)bh * NCH + ci];
        acc += w * pctx[((size_t)bh * NCH + ci) * DH + d];
    }
    int b = bh / NH, h = bh % NH;
    ctx_out[(size_t)b * DM + h * DH + d] = acc / L;
}

extern "C" void kernel_launch(void* const* d_in, const int* in_sizes, int n_in,
                              void* d_out, int out_size, void* d_ws, size_t ws_size,
                              hipStream_t stream)
{
    const float* hs   = (const float*)d_in[0];
    const float* kc   = (const float*)d_in[1];
    const float* vc   = (const float*)d_in[2];
    const float* mask = (const float*)d_in[3];
    const int*   cpos = (const int*)d_in[4];
    const int*   bt   = (const int*)d_in[5];
    const float* Wq   = (const float*)d_in[6];
    const float* bq   = (const float*)d_in[7];
    const float* Wk   = (const float*)d_in[8];
    const float* bk   = (const float*)d_in[9];
    const float* Wv   = (const float*)d_in[10];
    const float* bv   = (const float*)d_in[11];
    const float* Wo   = (const float*)d_in[12];
    const float* bo   = (const float*)d_in[13];
    float* out = (float*)d_out;

    float* ws = (float*)d_ws;
    float* ws_qkv = ws;                                   // q,k_new,v_new: 3*B*DM
    float* pm   = ws + (size_t)3 * NB_B * DM;             // B*H*NCH
    float* pl   = pm + (size_t)NB_B * NH * NCH;           // B*H*NCH
    float* pctx = pl + (size_t)NB_B * NH * NCH;           // B*H*NCH*DH
    float* ctxf = pctx + (size_t)NB_B * NH * NCH * DH;    // B*DM

    void* args[] = {
        (void*)&hs, (void*)&kc, (void*)&vc, (void*)&mask,
        (void*)&cpos, (void*)&bt,
        (void*)&Wq, (void*)&bq, (void*)&Wk, (void*)&bk,
        (void*)&Wv, (void*)&bv, (void*)&Wo, (void*)&bo,
        (void*)&ws_qkv, (void*)&pm, (void*)&pl, (void*)&pctx,
        (void*)&ctxf, (void*)&out
    };
    hipError_t err = hipLaunchCooperativeKernel((const void*)fused_all,
                                                dim3(1024), dim3(256),
                                                args, 0, stream);
    if (err != hipSuccess) {
        // deterministic fallback: proven 4-kernel path (R10)
        hipLaunchKernelGGL(qkv_all, dim3(3 * DM / 8), dim3(256), 0, stream,
                           hs, Wq, bq, Wk, bk, Wv, bv, ws_qkv);
        hipLaunchKernelGGL(attn_partial, dim3(NB_B * NH * NCH), dim3(256), 0, stream,
                           kc, vc, mask, cpos, bt, ws_qkv, pm, pl, pctx);
        hipLaunchKernelGGL(attn_reduce, dim3(NB_B * NH), dim3(64), 0, stream,
                           pm, pl, pctx, ctxf);
        hipLaunchKernelGGL(out_all, dim3(DM / 4), dim3(128), 0, stream,
                           ctxf, Wo, bo, out);
    }
}

// Round 13
// 108.349 us; speedup vs baseline: 3.7926x; 3.7926x over previous
//
#include <hip/hip_runtime.h>
#include <hip/hip_bf16.h>

#define NB_B 16
#define NH 16
#define NBLK 32
#define BSZ 128
#define DH 64
#define DM 1024
#define KVLEN 4096
#define NCH 8
#define CHUNK 512

// ws layout (floats):
// 0                  : q      (B*DM)
// B*DM               : k_new  (B*DM)
// 2*B*DM             : v_new  (B*DM)
// 3*B*DM             : part_m (B*H*NCH)
// +B*H*NCH           : part_l (B*H*NCH)
// +B*H*NCH           : part_ctx (B*H*NCH*DH)
// +B*H*NCH*DH        : ctx    (B*DM)

// LDS-free projection: one 32-lane group per weight row, full row
// (8 float4/lane) in registers; activations read straight through L1/L2
// (hs is 64 KB -> L2-hot after first touch). No LDS -> no 2-blocks/CU
// residency cap; all 384 blocks resident in one scheduling round.
// (Math verified by the round-12 fused kernel, which passed correctness.)
__global__ __launch_bounds__(256) void qkv_all(
    const float* __restrict__ hs,
    const float* __restrict__ Wq, const float* __restrict__ bq,
    const float* __restrict__ Wk, const float* __restrict__ bk,
    const float* __restrict__ Wv, const float* __restrict__ bv,
    float* __restrict__ ws)
{
    int tid = threadIdx.x;
    int grp = tid >> 5, gl = tid & 31;      // 8 groups of 32 lanes
    int row = blockIdx.x * 8 + grp;         // 0 .. 3*DM-1
    int mm = row >> 10;                     // 0=q,1=k,2=v
    int o = row & (DM - 1);
    const float* W    = (mm == 0) ? Wq : (mm == 1) ? Wk : Wv;
    const float* bias = (mm == 0) ? bq : (mm == 1) ? bk : bv;
    const float4* wrow = (const float4*)(W + (size_t)o * DM);
    float4 w[8];
#pragma unroll
    for (int k = 0; k < 8; ++k) w[k] = wrow[gl + 32 * k];
    float bb = bias[o];

    for (int b = 0; b < NB_B; ++b) {
        const float4* x = (const float4*)(hs + (size_t)b * DM);
        float acc = 0.f;
#pragma unroll
        for (int k = 0; k < 8; ++k) {
            float4 xv = x[gl + 32 * k];
            acc += w[k].x * xv.x + w[k].y * xv.y + w[k].z * xv.z + w[k].w * xv.w;
        }
        acc += __shfl_xor(acc, 1);
        acc += __shfl_xor(acc, 2);
        acc += __shfl_xor(acc, 4);
        acc += __shfl_xor(acc, 8);
        acc += __shfl_xor(acc, 16);
        if (gl == 0)
            ws[(size_t)mm * (NB_B * DM) + (size_t)b * DM + o] = acc + bb;
    }
}

__global__ __launch_bounds__(256) void out_all(
    const float* __restrict__ ctx, const float* __restrict__ Wo,
    const float* __restrict__ bo, float* __restrict__ out)
{
    int tid = threadIdx.x;
    int grp = tid >> 5, gl = tid & 31;      // 8 groups of 32 lanes
    int o = blockIdx.x * 8 + grp;           // 0 .. DM-1
    const float4* wrow = (const float4*)(Wo + (size_t)o * DM);
    float4 w[8];
#pragma unroll
    for (int k = 0; k < 8; ++k) w[k] = wrow[gl + 32 * k];
    float bb = bo[o];

    for (int b = 0; b < NB_B; ++b) {
        const float4* x = (const float4*)(ctx + (size_t)b * DM);
        float acc = 0.f;
#pragma unroll
        for (int k = 0; k < 8; ++k) {
            float4 xv = x[gl + 32 * k];
            acc += w[k].x * xv.x + w[k].y * xv.y + w[k].z * xv.z + w[k].w * xv.w;
        }
        acc += __shfl_xor(acc, 1);
        acc += __shfl_xor(acc, 2);
        acc += __shfl_xor(acc, 4);
        acc += __shfl_xor(acc, 8);
        acc += __shfl_xor(acc, 16);
        if (gl == 0)
            out[(size_t)b * DM + o] = acc + bb;
    }
}

// 8-lane groups: each lane owns 8 contiguous floats of K/V; wave covers
// 8 positions per iteration. Balanced XCD mapping: id = c*256 + bh, so all
// 8 chunks of a (b,h) share id mod 8 -> same XCD (L2 reuse of duplicate
// physical blocks), while every XCD gets 2 heads of EVERY batch -> exactly
// balanced work across XCDs.
__global__ __launch_bounds__(256) void attn_partial(
    const float* __restrict__ kc, const float* __restrict__ vc,
    const float* __restrict__ mask,
    const int* __restrict__ cpos, const int* __restrict__ bt,
    const float* __restrict__ wsin,   // q, k_new, v_new
    float* __restrict__ pm, float* __restrict__ pl, float* __restrict__ pctx)
{
    int id = blockIdx.x;                    // 0..2047
    int c  = id >> 8;                       // 0..7
    int bh = id & 255;
    int b  = bh >> 4;
    int h  = bh & (NH - 1);

    int tid = threadIdx.x;
    int wave = tid >> 6, lane = tid & 63;
    int g = lane >> 3, gl = lane & 7;       // 8 groups of 8 lanes per wave

    int pos = cpos[b];
    int nvalid = pos + 1;
    int start = c * CHUNK;
    int end = min(start + CHUNK, nvalid);

    const float* q    = wsin + (size_t)b * DM + h * DH;
    const float* knew = wsin + (size_t)NB_B * DM + (size_t)b * DM + h * DH;
    const float* vnew = wsin + (size_t)2 * NB_B * DM + (size_t)b * DM + h * DH;

    float4 qv0 = ((const float4*)q)[gl * 2];
    float4 qv1 = ((const float4*)q)[gl * 2 + 1];
    int phys_new = bt[b * NBLK + (pos >> 7)];
    int off_new  = pos & (BSZ - 1);

    const float* mrow = mask + (size_t)bh * KVLEN;
    const int* btrow = bt + b * NBLK;
    const unsigned bh_base = (unsigned)bh * NBLK;

    float m = -1e30f, l = 0.f;
    float4 ctx0 = {0.f, 0.f, 0.f, 0.f};
    float4 ctx1 = {0.f, 0.f, 0.f, 0.f};

    int n = end - start;
    if (n > 0) {
        int nfull = n >> 5;                 // 32 positions per block-iteration
        int jg = start + wave * 8 + g;
#pragma unroll 2
        for (int it = 0; it < nfull; ++it) {
            int j = jg + it * 32;
            int blk = j >> 7;
            int p = j & (BSZ - 1);
            int ph = btrow[blk];
            bool isnew = (ph == phys_new) && (p == off_new);
            unsigned coff = ((bh_base + (unsigned)ph) * BSZ + (unsigned)p) * DH;
            const float4* kp = (const float4*)(isnew ? knew : (kc + coff));
            const float4* vp = (const float4*)(isnew ? vnew : (vc + coff));
            float4 k0 = kp[gl * 2], k1 = kp[gl * 2 + 1];
            float4 v0 = vp[gl * 2], v1 = vp[gl * 2 + 1];
            float sd = qv0.x * k0.x + qv0.y * k0.y + qv0.z * k0.z + qv0.w * k0.w
                     + qv1.x * k1.x + qv1.y * k1.y + qv1.z * k1.z + qv1.w * k1.w;
            sd += __shfl_xor(sd, 1);
            sd += __shfl_xor(sd, 2);
            sd += __shfl_xor(sd, 4);
            float sc = sd + mrow[j];
            float newm = fmaxf(m, sc);
            float scale = __expf(m - newm);
            float pr = __expf(sc - newm);
            l = l * scale + pr;
            ctx0.x = ctx0.x * scale + pr * v0.x;
            ctx0.y = ctx0.y * scale + pr * v0.y;
            ctx0.z = ctx0.z * scale + pr * v0.z;
            ctx0.w = ctx0.w * scale + pr * v0.w;
            ctx1.x = ctx1.x * scale + pr * v1.x;
            ctx1.y = ctx1.y * scale + pr * v1.y;
            ctx1.z = ctx1.z * scale + pr * v1.z;
            ctx1.w = ctx1.w * scale + pr * v1.w;
            m = newm;
        }
        if (n & 31) {
            int j = jg + nfull * 32;
            bool valid = (j < end);
            float4 k0 = {0,0,0,0}, k1 = {0,0,0,0};
            float4 v0 = {0,0,0,0}, v1 = {0,0,0,0};
            float msk = 0.f;
            if (valid) {
                int blk = j >> 7;
                int p = j & (BSZ - 1);
                int ph = btrow[blk];
                bool isnew = (ph == phys_new) && (p == off_new);
                unsigned coff = ((bh_base + (unsigned)ph) * BSZ + (unsigned)p) * DH;
                const float4* kp = (const float4*)(isnew ? knew : (kc + coff));
                const float4* vp = (const float4*)(isnew ? vnew : (vc + coff));
                k0 = kp[gl * 2]; k1 = kp[gl * 2 + 1];
                v0 = vp[gl * 2]; v1 = vp[gl * 2 + 1];
                msk = mrow[j];
            }
            float sd = qv0.x * k0.x + qv0.y * k0.y + qv0.z * k0.z + qv0.w * k0.w
                     + qv1.x * k1.x + qv1.y * k1.y + qv1.z * k1.z + qv1.w * k1.w;
            sd += __shfl_xor(sd, 1);
            sd += __shfl_xor(sd, 2);
            sd += __shfl_xor(sd, 4);
            float sc = valid ? (sd + msk) : -1e30f;
            float newm = fmaxf(m, sc);
            float scale = __expf(m - newm);
            float pr = valid ? __expf(sc - newm) : 0.f;
            l = l * scale + pr;
            ctx0.x = ctx0.x * scale + pr * v0.x;
            ctx0.y = ctx0.y * scale + pr * v0.y;
            ctx0.z = ctx0.z * scale + pr * v0.z;
            ctx0.w = ctx0.w * scale + pr * v0.w;
            ctx1.x = ctx1.x * scale + pr * v1.x;
            ctx1.y = ctx1.y * scale + pr * v1.y;
            ctx1.z = ctx1.z * scale + pr * v1.z;
            ctx1.w = ctx1.w * scale + pr * v1.w;
            m = newm;
        }
    }

    // combine 32 groups (4 waves x 8 groups); each group's ctx spans DH via
    // 8 lanes x 8 floats
    __shared__ float gm[32], glv[32];
    __shared__ float gctx[32][DH];
    int gid = wave * 8 + g;
    if (gl == 0) { gm[gid] = m; glv[gid] = l; }
    *((float4*)&gctx[gid][gl * 8])     = ctx0;
    *((float4*)&gctx[gid][gl * 8 + 4]) = ctx1;
    __syncthreads();

    if (tid < DH) {
        int d = tid;
        float M = -1e30f;
#pragma unroll
        for (int i = 0; i < 32; ++i) M = fmaxf(M, gm[i]);
        float L = 0.f, acc = 0.f;
#pragma unroll
        for (int i = 0; i < 32; ++i) {
            float w = __expf(gm[i] - M);
            L += w * glv[i];
            acc += w * gctx[i][d];
        }
        size_t pi = (size_t)bh * NCH + c;
        if (d == 0) { pm[pi] = M; pl[pi] = L; }
        pctx[pi * DH + d] = acc;
    }
}

__global__ __launch_bounds__(64) void attn_reduce(
    const float* __restrict__ pm, const float* __restrict__ pl,
    const float* __restrict__ pctx, float* __restrict__ ctx_out)
{
    int bh = blockIdx.x;       // b*H + h
    int d = threadIdx.x;       // 0..63
    float M = -1e30f;
#pragma unroll
    for (int ci = 0; ci < NCH; ++ci) M = fmaxf(M, pm[(size_t)bh * NCH + ci]);
    float L = 0.f, acc = 0.f;
#pragma unroll
    for (int ci = 0; ci < NCH; ++ci) {
        float w = __expf(pm[(size_t)bh * NCH + ci] - M);
        L += w * pl[(size_t)bh * NCH + ci];
        acc += w * pctx[((size_t)bh * NCH + ci) * DH + d];
    }
    int b = bh / NH, h = bh % NH;
    ctx_out[(size_t)b * DM + h * DH + d] = acc / L;
}

extern "C" void kernel_launch(void* const* d_in, const int* in_sizes, int n_in,
                              void* d_out, int out_size, void* d_ws, size_t ws_size,
                              hipStream_t stream)
{
    const float* hs   = (const float*)d_in[0];
    const float* kc   = (const float*)d_in[1];
    const float* vc   = (const float*)d_in[2];
    const float* mask = (const float*)d_in[3];
    const int*   cpos = (const int*)d_in[4];
    const int*   bt   = (const int*)d_in[5];
    const float* Wq   = (const float*)d_in[6];
    const float* bq   = (const float*)d_in[7];
    const float* Wk   = (const float*)d_in[8];
    const float* bk   = (const float*)d_in[9];
    const float* Wv   = (const float*)d_in[10];
    const float* bv   = (const float*)d_in[11];
    const float* Wo   = (const float*)d_in[12];
    const float* bo   = (const float*)d_in[13];
    float* out = (float*)d_out;

    float* ws = (float*)d_ws;
    float* ws_qkv = ws;                                   // q,k_new,v_new: 3*B*DM
    float* pm   = ws + (size_t)3 * NB_B * DM;             // B*H*NCH
    float* pl   = pm + (size_t)NB_B * NH * NCH;           // B*H*NCH
    float* pctx = pl + (size_t)NB_B * NH * NCH;           // B*H*NCH*DH
    float* ctxf = pctx + (size_t)NB_B * NH * NCH * DH;    // B*DM

    hipLaunchKernelGGL(qkv_all, dim3(3 * DM / 8), dim3(256), 0, stream,
                       hs, Wq, bq, Wk, bk, Wv, bv, ws_qkv);

    hipLaunchKernelGGL(attn_partial, dim3(NB_B * NH * NCH), dim3(256), 0, stream,
                       kc, vc, mask, cpos, bt, ws_qkv, pm, pl, pctx);

    hipLaunchKernelGGL(attn_reduce, dim3(NB_B * NH), dim3(64), 0, stream,
                       pm, pl, pctx, ctxf);

    hipLaunchKernelGGL(out_all, dim3(DM / 8), dim3(256), 0, stream,
                       ctxf, Wo, bo, out);
}

// Round 14
// 60.339 us; speedup vs baseline: 6.8102x; 1.7957x over previous
//
#include <hip/hip_runtime.h>
#include <hip/hip_bf16.h>

#define NB_B 16
#define NH 16
#define NBLK 32
#define BSZ 128
#define DH 64
#define DM 1024
#define KVLEN 4096
#define NCH 8
#define CHUNK 512

// ws layout (floats):
// 0                  : q      (B*DM)
// B*DM               : k_new  (B*DM)
// 2*B*DM             : v_new  (B*DM)
// 3*B*DM             : part_m (B*H*NCH)
// +B*H*NCH           : part_l (B*H*NCH)
// +B*H*NCH           : part_ctx (B*H*NCH*DH)
// +B*H*NCH*DH        : ctx    (B*DM)

// One 32-lane group per weight row; full row (8 float4/lane) in registers;
// loop over all 16 batches staged in LDS (LDS staging is essential: R13's
// direct-from-global variant cost +46 us — the 16 serial batch dots need
// LDS-latency operands, not L1/L2 round-trips). Weights stream from HBM once.
__global__ __launch_bounds__(256) void qkv_all(
    const float* __restrict__ hs,
    const float* __restrict__ Wq, const float* __restrict__ bq,
    const float* __restrict__ Wk, const float* __restrict__ bk,
    const float* __restrict__ Wv, const float* __restrict__ bv,
    float* __restrict__ ws)
{
    __shared__ float sh[NB_B][DM];          // 64 KB: all batches' hidden states
    int tid = threadIdx.x;
#pragma unroll
    for (int i = 0; i < 16; ++i) {
        int idx = i * 256 + tid;            // float4 index, 4096 total
        ((float4*)sh)[idx] = ((const float4*)hs)[idx];
    }
    __syncthreads();

    int grp = tid >> 5, gl = tid & 31;      // 8 groups of 32 lanes
    int row = blockIdx.x * 8 + grp;         // 0 .. 3*DM-1
    int m = row >> 10;                      // 0=q,1=k,2=v
    int o = row & (DM - 1);
    const float* W    = (m == 0) ? Wq : (m == 1) ? Wk : Wv;
    const float* bias = (m == 0) ? bq : (m == 1) ? bk : bv;
    const float4* wrow = (const float4*)(W + (size_t)o * DM);
    float4 w[8];
#pragma unroll
    for (int k = 0; k < 8; ++k) w[k] = wrow[gl + 32 * k];
    float bb = bias[o];

    for (int b = 0; b < NB_B; ++b) {
        const float4* x = (const float4*)sh[b];
        float acc = 0.f;
#pragma unroll
        for (int k = 0; k < 8; ++k) {
            float4 xv = x[gl + 32 * k];
            acc += w[k].x * xv.x + w[k].y * xv.y + w[k].z * xv.z + w[k].w * xv.w;
        }
        acc += __shfl_xor(acc, 1);
        acc += __shfl_xor(acc, 2);
        acc += __shfl_xor(acc, 4);
        acc += __shfl_xor(acc, 8);
        acc += __shfl_xor(acc, 16);
        if (gl == 0)
            ws[(size_t)m * (NB_B * DM) + (size_t)b * DM + o] = acc + bb;
    }
}

__global__ __launch_bounds__(128) void out_all(
    const float* __restrict__ ctx, const float* __restrict__ Wo,
    const float* __restrict__ bo, float* __restrict__ out)
{
    __shared__ float sh[NB_B][DM];          // 64 KB: all batches' context
    int tid = threadIdx.x;
#pragma unroll
    for (int i = 0; i < 32; ++i) {
        int idx = i * 128 + tid;
        ((float4*)sh)[idx] = ((const float4*)ctx)[idx];
    }
    __syncthreads();

    int grp = tid >> 5, gl = tid & 31;      // 4 groups of 32 lanes
    int o = blockIdx.x * 4 + grp;           // 0 .. DM-1
    const float4* wrow = (const float4*)(Wo + (size_t)o * DM);
    float4 w[8];
#pragma unroll
    for (int k = 0; k < 8; ++k) w[k] = wrow[gl + 32 * k];
    float bb = bo[o];

    for (int b = 0; b < NB_B; ++b) {
        const float4* x = (const float4*)sh[b];
        float acc = 0.f;
#pragma unroll
        for (int k = 0; k < 8; ++k) {
            float4 xv = x[gl + 32 * k];
            acc += w[k].x * xv.x + w[k].y * xv.y + w[k].z * xv.z + w[k].w * xv.w;
        }
        acc += __shfl_xor(acc, 1);
        acc += __shfl_xor(acc, 2);
        acc += __shfl_xor(acc, 4);
        acc += __shfl_xor(acc, 8);
        acc += __shfl_xor(acc, 16);
        if (gl == 0)
            out[(size_t)b * DM + o] = acc + bb;
    }
}

// 8-lane groups: each lane owns 8 contiguous floats of K/V; wave covers
// 8 positions per iteration. Balanced XCD mapping: id = c*256 + bh, so all
// 8 chunks of a (b,h) share id mod 8 -> same XCD (L2 reuse of duplicate
// physical blocks), while every XCD gets 2 heads of EVERY batch -> exactly
// balanced work across XCDs. CHUNK=512.
__global__ __launch_bounds__(256) void attn_partial(
    const float* __restrict__ kc, const float* __restrict__ vc,
    const float* __restrict__ mask,
    const int* __restrict__ cpos, const int* __restrict__ bt,
    const float* __restrict__ wsin,   // q, k_new, v_new
    float* __restrict__ pm, float* __restrict__ pl, float* __restrict__ pctx)
{
    int id = blockIdx.x;                    // 0..2047
    int c  = id >> 8;                       // 0..7
    int bh = id & 255;
    int b  = bh >> 4;
    int h  = bh & (NH - 1);

    int tid = threadIdx.x;
    int wave = tid >> 6, lane = tid & 63;
    int g = lane >> 3, gl = lane & 7;       // 8 groups of 8 lanes per wave

    int pos = cpos[b];
    int nvalid = pos + 1;
    int start = c * CHUNK;
    int end = min(start + CHUNK, nvalid);

    const float* q    = wsin + (size_t)b * DM + h * DH;
    const float* knew = wsin + (size_t)NB_B * DM + (size_t)b * DM + h * DH;
    const float* vnew = wsin + (size_t)2 * NB_B * DM + (size_t)b * DM + h * DH;

    float4 qv0 = ((const float4*)q)[gl * 2];
    float4 qv1 = ((const float4*)q)[gl * 2 + 1];
    int phys_new = bt[b * NBLK + (pos >> 7)];
    int off_new  = pos & (BSZ - 1);

    const float* mrow = mask + (size_t)bh * KVLEN;
    const int* btrow = bt + b * NBLK;
    const unsigned bh_base = (unsigned)bh * NBLK;

    float m = -1e30f, l = 0.f;
    float4 ctx0 = {0.f, 0.f, 0.f, 0.f};
    float4 ctx1 = {0.f, 0.f, 0.f, 0.f};

    int n = end - start;
    if (n > 0) {
        int nfull = n >> 5;                 // 32 positions per block-iteration
        int jg = start + wave * 8 + g;
#pragma unroll 2
        for (int it = 0; it < nfull; ++it) {
            int j = jg + it * 32;
            int blk = j >> 7;
            int p = j & (BSZ - 1);
            int ph = btrow[blk];
            bool isnew = (ph == phys_new) && (p == off_new);
            unsigned coff = ((bh_base + (unsigned)ph) * BSZ + (unsigned)p) * DH;
            const float4* kp = (const float4*)(isnew ? knew : (kc + coff));
            const float4* vp = (const float4*)(isnew ? vnew : (vc + coff));
            float4 k0 = kp[gl * 2], k1 = kp[gl * 2 + 1];
            float4 v0 = vp[gl * 2], v1 = vp[gl * 2 + 1];
            float sd = qv0.x * k0.x + qv0.y * k0.y + qv0.z * k0.z + qv0.w * k0.w
                     + qv1.x * k1.x + qv1.y * k1.y + qv1.z * k1.z + qv1.w * k1.w;
            sd += __shfl_xor(sd, 1);
            sd += __shfl_xor(sd, 2);
            sd += __shfl_xor(sd, 4);
            float sc = sd + mrow[j];
            float newm = fmaxf(m, sc);
            float scale = __expf(m - newm);
            float pr = __expf(sc - newm);
            l = l * scale + pr;
            ctx0.x = ctx0.x * scale + pr * v0.x;
            ctx0.y = ctx0.y * scale + pr * v0.y;
            ctx0.z = ctx0.z * scale + pr * v0.z;
            ctx0.w = ctx0.w * scale + pr * v0.w;
            ctx1.x = ctx1.x * scale + pr * v1.x;
            ctx1.y = ctx1.y * scale + pr * v1.y;
            ctx1.z = ctx1.z * scale + pr * v1.z;
            ctx1.w = ctx1.w * scale + pr * v1.w;
            m = newm;
        }
        if (n & 31) {
            int j = jg + nfull * 32;
            bool valid = (j < end);
            float4 k0 = {0,0,0,0}, k1 = {0,0,0,0};
            float4 v0 = {0,0,0,0}, v1 = {0,0,0,0};
            float msk = 0.f;
            if (valid) {
                int blk = j >> 7;
                int p = j & (BSZ - 1);
                int ph = btrow[blk];
                bool isnew = (ph == phys_new) && (p == off_new);
                unsigned coff = ((bh_base + (unsigned)ph) * BSZ + (unsigned)p) * DH;
                const float4* kp = (const float4*)(isnew ? knew : (kc + coff));
                const float4* vp = (const float4*)(isnew ? vnew : (vc + coff));
                k0 = kp[gl * 2]; k1 = kp[gl * 2 + 1];
                v0 = vp[gl * 2]; v1 = vp[gl * 2 + 1];
                msk = mrow[j];
            }
            float sd = qv0.x * k0.x + qv0.y * k0.y + qv0.z * k0.z + qv0.w * k0.w
                     + qv1.x * k1.x + qv1.y * k1.y + qv1.z * k1.z + qv1.w * k1.w;
            sd += __shfl_xor(sd, 1);
            sd += __shfl_xor(sd, 2);
            sd += __shfl_xor(sd, 4);
            float sc = valid ? (sd + msk) : -1e30f;
            float newm = fmaxf(m, sc);
            float scale = __expf(m - newm);
            float pr = valid ? __expf(sc - newm) : 0.f;
            l = l * scale + pr;
            ctx0.x = ctx0.x * scale + pr * v0.x;
            ctx0.y = ctx0.y * scale + pr * v0.y;
            ctx0.z = ctx0.z * scale + pr * v0.z;
            ctx0.w = ctx0.w * scale + pr * v0.w;
            ctx1.x = ctx1.x * scale + pr * v1.x;
            ctx1.y = ctx1.y * scale + pr * v1.y;
            ctx1.z = ctx1.z * scale + pr * v1.z;
            ctx1.w = ctx1.w * scale + pr * v1.w;
            m = newm;
        }
    }

    // combine 32 groups (4 waves x 8 groups); each group's ctx spans DH via
    // 8 lanes x 8 floats
    __shared__ float gm[32], glv[32];
    __shared__ float gctx[32][DH];
    int gid = wave * 8 + g;
    if (gl == 0) { gm[gid] = m; glv[gid] = l; }
    *((float4*)&gctx[gid][gl * 8])     = ctx0;
    *((float4*)&gctx[gid][gl * 8 + 4]) = ctx1;
    __syncthreads();

    if (tid < DH) {
        int d = tid;
        float M = -1e30f;
#pragma unroll
        for (int i = 0; i < 32; ++i) M = fmaxf(M, gm[i]);
        float L = 0.f, acc = 0.f;
#pragma unroll
        for (int i = 0; i < 32; ++i) {
            float w = __expf(gm[i] - M);
            L += w * glv[i];
            acc += w * gctx[i][d];
        }
        size_t pi = (size_t)bh * NCH + c;
        if (d == 0) { pm[pi] = M; pl[pi] = L; }
        pctx[pi * DH + d] = acc;
    }
}

__global__ __launch_bounds__(64) void attn_reduce(
    const float* __restrict__ pm, const float* __restrict__ pl,
    const float* __restrict__ pctx, float* __restrict__ ctx_out)
{
    int bh = blockIdx.x;       // b*H + h
    int d = threadIdx.x;       // 0..63
    float M = -1e30f;
#pragma unroll
    for (int ci = 0; ci < NCH; ++ci) M = fmaxf(M, pm[(size_t)bh * NCH + ci]);
    float L = 0.f, acc = 0.f;
#pragma unroll
    for (int ci = 0; ci < NCH; ++ci) {
        float w = __expf(pm[(size_t)bh * NCH + ci] - M);
        L += w * pl[(size_t)bh * NCH + ci];
        acc += w * pctx[((size_t)bh * NCH + ci) * DH + d];
    }
    int b = bh / NH, h = bh % NH;
    ctx_out[(size_t)b * DM + h * DH + d] = acc / L;
}

extern "C" void kernel_launch(void* const* d_in, const int* in_sizes, int n_in,
                              void* d_out, int out_size, void* d_ws, size_t ws_size,
                              hipStream_t stream)
{
    const float* hs   = (const float*)d_in[0];
    const float* kc   = (const float*)d_in[1];
    const float* vc   = (const float*)d_in[2];
    const float* mask = (const float*)d_in[3];
    const int*   cpos = (const int*)d_in[4];
    const int*   bt   = (const int*)d_in[5];
    const float* Wq   = (const float*)d_in[6];
    const float* bq   = (const float*)d_in[7];
    const float* Wk   = (const float*)d_in[8];
    const float* bk   = (const float*)d_in[9];
    const float* Wv   = (const float*)d_in[10];
    const float* bv   = (const float*)d_in[11];
    const float* Wo   = (const float*)d_in[12];
    const float* bo   = (const float*)d_in[13];
    float* out = (float*)d_out;

    float* ws = (float*)d_ws;
    float* ws_qkv = ws;                                   // q,k_new,v_new: 3*B*DM
    float* pm   = ws + (size_t)3 * NB_B * DM;             // B*H*NCH
    float* pl   = pm + (size_t)NB_B * NH * NCH;           // B*H*NCH
    float* pctx = pl + (size_t)NB_B * NH * NCH;           // B*H*NCH*DH
    float* ctxf = pctx + (size_t)NB_B * NH * NCH * DH;    // B*DM

    hipLaunchKernelGGL(qkv_all, dim3(3 * DM / 8), dim3(256), 0, stream,
                       hs, Wq, bq, Wk, bk, Wv, bv, ws_qkv);

    hipLaunchKernelGGL(attn_partial, dim3(NB_B * NH * NCH), dim3(256), 0, stream,
                       kc, vc, mask, cpos, bt, ws_qkv, pm, pl, pctx);

    hipLaunchKernelGGL(attn_reduce, dim3(NB_B * NH), dim3(64), 0, stream,
                       pm, pl, pctx, ctxf);

    hipLaunchKernelGGL(out_all, dim3(DM / 4), dim3(128), 0, stream,
                       ctxf, Wo, bo, out);
}